// Round 9
// baseline (217.747 us; speedup 1.0000x reference)
//
#include <hip/hip_runtime.h>
#include <hip/hip_bf16.h>

// B=4, M=2048, D=1024, H=16, K=V=64
#define B_  4
#define M_  2048
#define D_  1024
#define H_  16

typedef __attribute__((ext_vector_type(8)))  short bf16x8;
typedef __attribute__((ext_vector_type(4)))  float f32x4;
typedef __attribute__((ext_vector_type(16))) float f32x16;
typedef __attribute__((ext_vector_type(4)))  unsigned short u16x4;
typedef __attribute__((ext_vector_type(2)))  unsigned int uint2v;

#define MFMA16(a, b, c) __builtin_amdgcn_mfma_f32_16x16x32_bf16((a), (b), (c), 0, 0, 0)
#define MFMA32(a, b, c) __builtin_amdgcn_mfma_f32_32x32x16_bf16((a), (b), (c), 0, 0, 0)

// Q pre-scale: 1/sqrt(64) * log2(e)  (softmax done in exp2 domain)
#define QSCALE 0.18033688011112042f

__device__ __forceinline__ unsigned short f2b(float f) {
  union { float f; unsigned u; } v; v.f = f;
  unsigned r = v.u + 0x7FFF + ((v.u >> 16) & 1);   // RNE
  return (unsigned short)(r >> 16);
}

__device__ __forceinline__ unsigned cvtpk(float lo, float hi) {
  unsigned r;
  asm("v_cvt_pk_bf16_f32 %0, %1, %2" : "=v"(r) : "v"(lo), "v"(hi));
  return r;
}

// GEMM-tile swizzle for the 128x128 body (out_gemm).
__device__ __forceinline__ int swzb(int byte) {
  return byte ^ (((byte >> 7) & 7) << 4);
}

// Attention swizzle: 256B macro-rows.
#define SWZ256(L) ((L) ^ ((((L) >> 8) & 15) << 4))

#define GLOAD16(gsrc, ldst)                                                     \
  __builtin_amdgcn_global_load_lds(                                             \
      (const __attribute__((address_space(1))) void*)(gsrc),                    \
      (__attribute__((address_space(3))) void*)(ldst), 16, 0, 0)

// ---------------------------------------------------------------------------
// Conversions (unchanged)
// ---------------------------------------------------------------------------
__global__ __launch_bounds__(256) void convert_x_kernel(
    const float* __restrict__ x, short* __restrict__ xb) {
  const size_t i = ((size_t)blockIdx.x * 256 + threadIdx.x) * 8;
  float4 a = *(const float4*)(x + i);
  float4 b = *(const float4*)(x + i + 4);
  bf16x8 o;
  o[0] = (short)f2b(a.x); o[1] = (short)f2b(a.y); o[2] = (short)f2b(a.z); o[3] = (short)f2b(a.w);
  o[4] = (short)f2b(b.x); o[5] = (short)f2b(b.y); o[6] = (short)f2b(b.z); o[7] = (short)f2b(b.w);
  *(bf16x8*)(xb + i) = o;
}

// Wt[n][d], n = which*1024 + h*64 + kc ; Wt[n][d] = P_which[h][d][kc]
__global__ __launch_bounds__(256) void convert_w_kernel(
    const float* __restrict__ Pq, const float* __restrict__ Pk,
    const float* __restrict__ Pv, short* __restrict__ Wt) {
  const int idx = blockIdx.x * 256 + threadIdx.x;   // n*256 + d/4
  const int n = idx >> 8, d0 = (idx & 255) * 4;
  const int which = n >> 10, h = (n >> 6) & 15, kc = n & 63;
  const float* P = (which == 0) ? Pq : (which == 1) ? Pk : Pv;
  const float* p = P + ((size_t)h * D_ + d0) * 64 + kc;
  u16x4 o;
  o[0] = f2b(p[0]); o[1] = f2b(p[64]); o[2] = f2b(p[128]); o[3] = f2b(p[192]);
  *(u16x4*)(Wt + (size_t)n * D_ + d0) = o;
}

// Wo[d][h*64+v] = P_o[h][d][v]
__global__ __launch_bounds__(256) void convert_wo_kernel(
    const float* __restrict__ Po, short* __restrict__ Wo) {
  const int idx = blockIdx.x * 256 + threadIdx.x;   // d*256 + hv/4
  const int d = idx >> 8, hv0 = (idx & 255) * 4;
  const int h = hv0 >> 6, v = hv0 & 63;
  float4 a = *(const float4*)(Po + ((size_t)h * D_ + d) * 64 + v);
  u16x4 o;
  o[0] = f2b(a.x); o[1] = f2b(a.y); o[2] = f2b(a.z); o[3] = f2b(a.w);
  *(u16x4*)(Wo + (size_t)d * 1024 + hv0) = o;
}

// ---------------------------------------------------------------------------
// QKV GEMM — 8-phase 256x256 schedule (T2-free K-major layout, T3+T4+T5).
// 512 threads = 8 waves (2M x 4N), per-wave C = 128x64, BK=64, K=1024.
// LDS: A/B each 2buf x 2khalf x 16KB regions, total 128 KB.
//   Region layout (k-major): [kslot 0..3][256 rows][16B] -> linear staging,
//   conflict-free ds_read_b128 (lane stride 16B).
// Per iteration = 2 K-tiles = 8 phases; phase (buf,ks,mhalf): 16 MFMA.
// Stage 1 half (2 gload_lds) per phase; uniform vmcnt(8) at odd-phase close
// guarantees the next phase-pair's reads (12 in flight -> oldest 4 done).
// Tail: source-tile clamped to 15 (dummy stages keep vmcnt math steady).
// ---------------------------------------------------------------------------
__global__ __launch_bounds__(512, 2) void qkv_gemm_kernel(
    const short* __restrict__ xb, const short* __restrict__ Wt,
    short* __restrict__ Qw, short* __restrict__ Kw, short* __restrict__ Vt) {
  __shared__ __align__(16) char lds[131072];
  const int bid = blockIdx.x;                 // 384 blocks
  const int xcd = bid & 7, slot = bid >> 3;   // slot 0..47
  const int m0 = (xcd * 4 + (slot & 3)) * 256;
  const int n0 = (slot >> 2) * 256;
  const int t = threadIdx.x, lane = t & 63, w = t >> 6;
  const int wm = w >> 2, wn = w & 3;          // 2 x 4 waves
  const int lrow = lane & 15, lgrp = lane >> 4;

  const char* Agc = (const char*)xb + (size_t)m0 * 2048;
  const char* Bgc = (const char*)Wt + (size_t)n0 * 2048;

  // stage one 16KB region (2 x gload_lds of 8KB)
  auto stageA = [&](int b, int ks, int kt) {
#pragma unroll
    for (int i = 0; i < 2; ++i) {
      const int L = i * 8192 + t * 16;
      const int sk = L >> 12, row = (L & 4095) >> 4;
      GLOAD16(Agc + (size_t)row * 2048 + kt * 128 + ks * 64 + sk * 16,
              lds + (b * 2 + ks) * 16384 + i * 8192 + w * 1024);
    }
  };
  auto stageB = [&](int b, int ks, int kt) {
#pragma unroll
    for (int i = 0; i < 2; ++i) {
      const int L = i * 8192 + t * 16;
      const int sk = L >> 12, row = (L & 4095) >> 4;
      GLOAD16(Bgc + (size_t)row * 2048 + kt * 128 + ks * 64 + sk * 16,
              lds + 65536 + (b * 2 + ks) * 16384 + i * 8192 + w * 1024);
    }
  };

  f32x4 acc[8][4] = {};

  // prologue: tile0 (all 4 halves) + tile1 ks0 (2 halves) = 12 loads
  stageA(0, 0, 0); stageB(0, 0, 0);
  stageA(0, 1, 0); stageB(0, 1, 0);
  stageA(1, 0, 1); stageB(1, 0, 1);
  asm volatile("s_waitcnt vmcnt(8)" ::: "memory");   // tile0 ks0 landed
  __builtin_amdgcn_s_barrier();

  for (int it = 0; it < 8; ++it) {
    const int k1 = 2 * it + 1;                        // <= 15 always
    const int k2 = (2 * it + 2 > 15) ? 15 : 2 * it + 2;
    const int k3 = (2 * it + 3 > 15) ? 15 : 2 * it + 3;
    bf16x8 bfr[4];
#pragma unroll
    for (int p = 0; p < 8; ++p) {
      const int buf = p >> 2, ks = (p >> 1) & 1, mh = p & 1;
      const char* Ar = lds + (buf * 2 + ks) * 16384;
      const char* Br = lds + 65536 + (buf * 2 + ks) * 16384;
      // A frags for this m-half (4 reads); B frags read at mh==0, reused mh==1
      bf16x8 afr[4];
#pragma unroll
      for (int f = 0; f < 4; ++f)
        afr[f] = *(const bf16x8*)(Ar + lgrp * 4096 +
                                  (wm * 128 + (mh * 4 + f) * 16 + lrow) * 16);
      if (mh == 0) {
#pragma unroll
        for (int f = 0; f < 4; ++f)
          bfr[f] = *(const bf16x8*)(Br + lgrp * 4096 +
                                    (wn * 64 + f * 16 + lrow) * 16);
      }
      // stage schedule: one half per phase (regions provably free)
      if (p == 0) stageA(1, 1, k1);
      if (p == 1) stageB(1, 1, k1);
      if (p == 2) stageA(0, 0, k2);
      if (p == 3) stageB(0, 0, k2);
      if (p == 4) stageA(0, 1, k2);
      if (p == 5) stageB(0, 1, k2);
      if (p == 6) stageA(1, 0, k3);
      if (p == 7) stageB(1, 0, k3);

      __builtin_amdgcn_s_barrier();          // phase open
      __builtin_amdgcn_s_setprio(1);
#pragma unroll
      for (int f = 0; f < 4; ++f)
#pragma unroll
        for (int nf = 0; nf < 4; ++nf)
          acc[mh * 4 + f][nf] = MFMA16(afr[f], bfr[nf], acc[mh * 4 + f][nf]);
      __builtin_amdgcn_s_setprio(0);
      if (mh == 1) asm volatile("s_waitcnt vmcnt(8)" ::: "memory");
      __builtin_amdgcn_s_barrier();          // phase close
    }
  }
  asm volatile("s_waitcnt vmcnt(0)" ::: "memory");    // drain dummy stages

  // epilogue: which is block-constant (n0 aligned to 256, 1024 | boundaries)
  const int which = n0 >> 10;
#pragma unroll
  for (int nf = 0; nf < 4; ++nf) {
    const int n = n0 + wn * 64 + nf * 16 + lrow;
    const int h = (n >> 6) & 15, kc = n & 63;
#pragma unroll
    for (int mf = 0; mf < 8; ++mf) {
      const int row0 = m0 + wm * 128 + mf * 16 + lgrp * 4;
      const int b = row0 >> 11, mm = row0 & 2047;
      const int bh = b * 16 + h;
      if (which == 2) {
        u16x4 o;
        o[0] = f2b(acc[mf][nf][0]); o[1] = f2b(acc[mf][nf][1]);
        o[2] = f2b(acc[mf][nf][2]); o[3] = f2b(acc[mf][nf][3]);
        *(u16x4*)(Vt + ((size_t)bh * 64 + kc) * M_ + mm) = o;
      } else {
        short* outp = (which == 0 ? Qw : Kw) + ((size_t)bh * M_ + mm) * 64 + kc;
        const float scale = (which == 0) ? QSCALE : 1.0f;
#pragma unroll
        for (int r = 0; r < 4; ++r)
          outp[(size_t)r * 64] = (short)f2b(acc[mf][nf][r] * scale);
      }
    }
  }
}

// ---------------------------------------------------------------------------
// 128x128 pipelined body (r8, proven) — kept for out_gemm.
// ---------------------------------------------------------------------------
__device__ __forceinline__ void gemm_body_128x128(
    const char* __restrict__ Agc, const char* __restrict__ Bgc,
    short* AsBase, short* BsBase, int t, int w, int lane,
    f32x4 (&acc)[4][4])
{
  const int wr = (w >> 1) * 64, wc = (w & 1) * 64;
  const int lrow = lane & 15, lgrp = lane >> 4;

  auto stage = [&](int bi, int kt) {
    const int d2 = kt * 128;
#pragma unroll
    for (int i = 0; i < 4; ++i) {
      const int L = i * 4096 + t * 16;
      const int row = L >> 7;
      const int cs = (L & 127) ^ ((row & 7) << 4);
      GLOAD16(Agc + (size_t)row * 2048 + d2 + cs, (char*)AsBase + bi * 16384 + L);
      GLOAD16(Bgc + (size_t)row * 2048 + d2 + cs, (char*)BsBase + bi * 16384 + L);
    }
  };

  stage(0, 0);

  for (int kt = 0; kt < 16; ++kt) {
    const int cur = kt & 1;
    __builtin_amdgcn_s_barrier();
    if (kt + 1 < 16) {
      stage(cur ^ 1, kt + 1);
      asm volatile("s_waitcnt vmcnt(8)" ::: "memory");
    } else {
      asm volatile("s_waitcnt vmcnt(0)" ::: "memory");
    }
    __builtin_amdgcn_s_barrier();

    const char* Ac = (const char*)AsBase + cur * 16384;
    const char* Bc = (const char*)BsBase + cur * 16384;
#pragma unroll
    for (int ks = 0; ks < 2; ++ks) {
      bf16x8 a[4], b[4];
      const int cb = ks * 64 + lgrp * 16;
#pragma unroll
      for (int f = 0; f < 4; ++f) {
        a[f] = *(const bf16x8*)(Ac + swzb((wr + f * 16 + lrow) * 128 + cb));
        b[f] = *(const bf16x8*)(Bc + swzb((wc + f * 16 + lrow) * 128 + cb));
      }
      __builtin_amdgcn_s_setprio(1);
#pragma unroll
      for (int mf = 0; mf < 4; ++mf)
#pragma unroll
        for (int nf = 0; nf < 4; ++nf)
          acc[mf][nf] = MFMA16(a[mf], b[nf], acc[mf][nf]);
      __builtin_amdgcn_s_setprio(0);
    }
  }
}

// ---------------------------------------------------------------------------
// Output projection: y[8192][1024] = O2 @ Wo^T (unchanged from r8)
// ---------------------------------------------------------------------------
__global__ __launch_bounds__(256) void out_gemm_kernel(
    const short* __restrict__ O2, const short* __restrict__ Wo,
    float* __restrict__ y) {
  __shared__ short As[2][8192];
  __shared__ short Bs[2][8192];
  const int bid = blockIdx.x;                 // 512
  const int xcd = bid & 7, slot = bid >> 3;   // slot 0..63
  const int m0 = (xcd * 8 + (slot & 7)) * 128;
  const int n0 = (slot >> 3) * 128;
  const int t = threadIdx.x, lane = t & 63, w = t >> 6;

  f32x4 acc[4][4] = {};
  gemm_body_128x128((const char*)O2 + (size_t)m0 * 2048,
                    (const char*)Wo + (size_t)n0 * 2048,
                    &As[0][0], &Bs[0][0], t, w, lane, acc);

  const int wr = (w >> 1) * 64, wc = (w & 1) * 64;
  const int lrow = lane & 15, lgrp = lane >> 4;
#pragma unroll
  for (int mf = 0; mf < 4; ++mf)
#pragma unroll
    for (int nf = 0; nf < 4; ++nf) {
      const int n = n0 + wc + nf * 16 + lrow;
      const int row0 = m0 + wr + mf * 16 + lgrp * 4;
#pragma unroll
      for (int r = 0; r < 4; ++r)
        y[(size_t)(row0 + r) * 1024 + n] = acc[mf][nf][r];
    }
}

// ---------------------------------------------------------------------------
// Attention helpers (unchanged)
// ---------------------------------------------------------------------------
__device__ __forceinline__ void softmax_chunk(
    f32x16& s0, f32x16& s1, f32x16& o0, f32x16& o1,
    float& mrun, float& lrun, bf16x8 (&pf)[4])
{
  float tm[16];
#pragma unroll
  for (int r = 0; r < 16; ++r) tm[r] = fmaxf(s0[r], s1[r]);
#pragma unroll
  for (int st = 8; st > 0; st >>= 1)
#pragma unroll
    for (int r = 0; r < 8; ++r)
      if (r < st) tm[r] = fmaxf(tm[r], tm[r + st]);
  uint2v pm = __builtin_amdgcn_permlane32_swap(
      __float_as_uint(tm[0]), __float_as_uint(tm[0]), false, false);
  const float mtile = fmaxf(__uint_as_float(pm[0]), __uint_as_float(pm[1]));

  if (!__all(mtile <= mrun + 8.0f)) {
    const float mnew = fmaxf(mrun, mtile);
    const float alpha = __builtin_amdgcn_exp2f(mrun - mnew);
    mrun = mnew;
    lrun *= alpha;
    o0 *= alpha;
    o1 *= alpha;
  }
#pragma unroll
  for (int r = 0; r < 16; ++r) {
    s0[r] = __builtin_amdgcn_exp2f(s0[r] - mrun);
    s1[r] = __builtin_amdgcn_exp2f(s1[r] - mrun);
  }
#pragma unroll
  for (int c = 0; c < 4; ++c) {
    const f32x16& sv = (c < 2) ? s0 : s1;
    const int rb = (c & 1) * 8;
    unsigned a0 = cvtpk(sv[rb + 0], sv[rb + 1]);
    unsigned a1 = cvtpk(sv[rb + 2], sv[rb + 3]);
    unsigned b0 = cvtpk(sv[rb + 4], sv[rb + 5]);
    unsigned b1 = cvtpk(sv[rb + 6], sv[rb + 7]);
    uint2v t0 = __builtin_amdgcn_permlane32_swap(a0, b0, false, false);
    uint2v t1 = __builtin_amdgcn_permlane32_swap(a1, b1, false, false);
    union { unsigned u[4]; bf16x8 v; } pk;
    pk.u[0] = t0[0]; pk.u[1] = t1[0]; pk.u[2] = t0[1]; pk.u[3] = t1[1];
    pf[c] = pk.v;
  }
}

// ---------------------------------------------------------------------------
// Flash attention (unchanged from r8)
// ---------------------------------------------------------------------------
__global__ __launch_bounds__(256) void attn_kernel(
    const short* __restrict__ Qw, const short* __restrict__ Kw,
    const short* __restrict__ Vt, short* __restrict__ O2) {
  __shared__ short Ks[2][64 * 64];
  __shared__ short Vs[2][64 * 64];

  const int bid = blockIdx.x;                 // 1024 blocks
  const int chunk = 15 - (bid >> 6);          // heavy-first
  const int bh = bid & 63;                    // bh%8 == dispatch XCD
  const int q0 = chunk * 128;

  const int t = threadIdx.x, lane = t & 63, w = t >> 6;
  const int l31 = lane & 31, hi = lane >> 5;
  const int qw0 = q0 + w * 32;
  const int qabs = qw0 + l31;

  bf16x8 qfrag[4];
#pragma unroll
  for (int kc = 0; kc < 4; ++kc)
    qfrag[kc] = *(const bf16x8*)(Qw + ((size_t)bh * M_ + qabs) * 64 + kc * 16 + hi * 8);

  f32x16 o0 = {}, o1 = {};
  float mrun = -3.0e38f, lrun = 0.f;

  const char* Kg = (const char*)Kw + (size_t)bh * M_ * 128;
  const char* Vg = (const char*)Vt + (size_t)bh * 64 * M_ * 2;

  auto stage = [&](int bi, int j0_) {
#pragma unroll
    for (int i = 0; i < 2; ++i) {
      const int L  = i * 4096 + t * 16;
      const int Ls = SWZ256(L);
      const int row = Ls >> 7, col = Ls & 127;
      GLOAD16(Kg + (size_t)(j0_ + row) * 128 + col, (char*)Ks[bi] + i * 4096 + w * 1024);
      GLOAD16(Vg + (size_t)row * (M_ * 2) + (size_t)j0_ * 2 + col, (char*)Vs[bi] + i * 4096 + w * 1024);
    }
  };

  const int nt = (q0 + 128) >> 6;
  stage(0, 0);

  bf16x8 ones;
#pragma unroll
  for (int e = 0; e < 8; ++e) ones[e] = (short)0x3F80;

  for (int tt = 0; tt < nt; ++tt) {
    const int j0 = tt << 6;
    const int cur = tt & 1;
    __builtin_amdgcn_s_barrier();
    if (tt + 1 < nt) {
      stage(cur ^ 1, j0 + 64);
      asm volatile("s_waitcnt vmcnt(4)" ::: "memory");
    } else {
      asm volatile("s_waitcnt vmcnt(0)" ::: "memory");
    }
    __builtin_amdgcn_s_barrier();
    if (j0 >= qw0 + 32) continue;

    const char* Kc = (const char*)Ks[cur];
    const char* Vc = (const char*)Vs[cur];

    f32x16 s0 = {}, s1 = {};
    __builtin_amdgcn_s_setprio(1);
#pragma unroll
    for (int kc = 0; kc < 4; ++kc) {
      bf16x8 kf0 = *(const bf16x8*)(Kc + SWZ256(l31 * 128 + kc * 32 + hi * 16));
      s0 = MFMA32(kf0, qfrag[kc], s0);
      bf16x8 kf1 = *(const bf16x8*)(Kc + SWZ256((32 + l31) * 128 + kc * 32 + hi * 16));
      s1 = MFMA32(kf1, qfrag[kc], s1);
    }
    __builtin_amdgcn_s_setprio(0);

    if (j0 + 64 > qw0) {
#pragma unroll
      for (int r = 0; r < 16; ++r) {
        const int k0 = j0 + (r & 3) + 8 * (r >> 2) + 4 * hi;
        if (k0 > qabs)      s0[r] = -3.0e38f;
        if (k0 + 32 > qabs) s1[r] = -3.0e38f;
      }
    }

    bf16x8 pf[4];
    softmax_chunk(s0, s1, o0, o1, mrun, lrun, pf);

    f32x16 lacc = {};
    __builtin_amdgcn_s_setprio(1);
#pragma unroll
    for (int c = 0; c < 4; ++c) {
      bf16x8 vf0 = *(const bf16x8*)(Vc + SWZ256(l31 * 128 + c * 32 + hi * 16));
      o0 = MFMA32(vf0, pf[c], o0);
      bf16x8 vf1 = *(const bf16x8*)(Vc + SWZ256((32 + l31) * 128 + c * 32 + hi * 16));
      o1 = MFMA32(vf1, pf[c], o1);
      lacc = MFMA32(ones, pf[c], lacc);
    }
    __builtin_amdgcn_s_setprio(0);
    lrun += lacc[0];
  }

  const int b = bh >> 4, h = bh & 15;
  const float inv = 1.0f / lrun;
  short* orow = O2 + ((size_t)b * M_ + qabs) * 1024 + h * 64;
#pragma unroll
  for (int vb = 0; vb < 2; ++vb) {
    const f32x16& o = vb ? o1 : o0;
#pragma unroll
    for (int g = 0; g < 4; ++g) {
      const int vbase = vb * 32 + 8 * g + 4 * hi;
      u16x4 pkt;
      pkt[0] = f2b(o[g * 4 + 0] * inv);
      pkt[1] = f2b(o[g * 4 + 1] * inv);
      pkt[2] = f2b(o[g * 4 + 2] * inv);
      pkt[3] = f2b(o[g * 4 + 3] * inv);
      *(u16x4*)(orow + vbase) = pkt;
    }
  }
}

// ---------------------------------------------------------------------------
extern "C" void kernel_launch(void* const* d_in, const int* in_sizes, int n_in,
                              void* d_out, int out_size, void* d_ws, size_t ws_size,
                              hipStream_t stream) {
  const float* x  = (const float*)d_in[0];
  const float* Pq = (const float*)d_in[1];
  const float* Pk = (const float*)d_in[2];
  const float* Pv = (const float*)d_in[3];
  const float* Po = (const float*)d_in[4];
  float* y = (float*)d_out;

  short* ws = (short*)d_ws;
  const size_t NX = (size_t)B_ * M_ * D_;        // 8,388,608
  short* xb  = ws;                 ws += NX;
  short* Wt  = ws;                 ws += (size_t)3072 * 1024;
  short* Wo  = ws;                 ws += (size_t)1024 * 1024;
  short* Qw  = ws;                 ws += NX;
  short* Kw  = ws;                 ws += NX;
  short* Vt  = ws;                 ws += NX;
  short* O2  = ws;                 ws += NX;

  convert_x_kernel <<<4096, 256, 0, stream>>>(x, xb);
  convert_w_kernel <<<3072, 256, 0, stream>>>(Pq, Pk, Pv, Wt);
  convert_wo_kernel<<<1024, 256, 0, stream>>>(Po, Wo);
  qkv_gemm_kernel  <<<384,  512, 0, stream>>>(xb, Wt, Qw, Kw, Vt);
  attn_kernel      <<<1024, 256, 0, stream>>>(Qw, Kw, Vt, O2);
  out_gemm_kernel  <<<512,  256, 0, stream>>>(O2, Wo, y);
}

// Round 10
// 179.075 us; speedup vs baseline: 1.2160x; 1.2160x over previous
//
#include <hip/hip_runtime.h>
#include <hip/hip_bf16.h>

// B=4, M=2048, D=1024, H=16, K=V=64
#define B_  4
#define M_  2048
#define D_  1024
#define H_  16

typedef __attribute__((ext_vector_type(8)))  short bf16x8;
typedef __attribute__((ext_vector_type(4)))  float f32x4;
typedef __attribute__((ext_vector_type(16))) float f32x16;
typedef __attribute__((ext_vector_type(4)))  unsigned short u16x4;
typedef __attribute__((ext_vector_type(2)))  unsigned int uint2v;

#define MFMA16(a, b, c) __builtin_amdgcn_mfma_f32_16x16x32_bf16((a), (b), (c), 0, 0, 0)
#define MFMA32(a, b, c) __builtin_amdgcn_mfma_f32_32x32x16_bf16((a), (b), (c), 0, 0, 0)

// Q pre-scale: 1/sqrt(64) * log2(e)  (softmax done in exp2 domain)
#define QSCALE 0.18033688011112042f

__device__ __forceinline__ unsigned short f2b(float f) {
  union { float f; unsigned u; } v; v.f = f;
  unsigned r = v.u + 0x7FFF + ((v.u >> 16) & 1);   // RNE
  return (unsigned short)(r >> 16);
}

__device__ __forceinline__ unsigned cvtpk(float lo, float hi) {
  unsigned r;
  asm("v_cvt_pk_bf16_f32 %0, %1, %2" : "=v"(r) : "v"(lo), "v"(hi));
  return r;
}

// GEMM-tile swizzle: 128B rows, XOR 16B-slot bits 4-6 with row low bits.
__device__ __forceinline__ int swzb(int byte) {
  return byte ^ (((byte >> 7) & 7) << 4);
}

// Attention swizzle: 256B macro-rows.
#define SWZ256(L) ((L) ^ ((((L) >> 8) & 15) << 4))

#define GLOAD16(gsrc, ldst)                                                     \
  __builtin_amdgcn_global_load_lds(                                             \
      (const __attribute__((address_space(1))) void*)(gsrc),                    \
      (__attribute__((address_space(3))) void*)(ldst), 16, 0, 0)

// ---------------------------------------------------------------------------
// Conversions (unchanged)
// ---------------------------------------------------------------------------
__global__ __launch_bounds__(256) void convert_x_kernel(
    const float* __restrict__ x, short* __restrict__ xb) {
  const size_t i = ((size_t)blockIdx.x * 256 + threadIdx.x) * 8;
  float4 a = *(const float4*)(x + i);
  float4 b = *(const float4*)(x + i + 4);
  bf16x8 o;
  o[0] = (short)f2b(a.x); o[1] = (short)f2b(a.y); o[2] = (short)f2b(a.z); o[3] = (short)f2b(a.w);
  o[4] = (short)f2b(b.x); o[5] = (short)f2b(b.y); o[6] = (short)f2b(b.z); o[7] = (short)f2b(b.w);
  *(bf16x8*)(xb + i) = o;
}

// Wt[n][d], n = which*1024 + h*64 + kc ; Wt[n][d] = P_which[h][d][kc]
__global__ __launch_bounds__(256) void convert_w_kernel(
    const float* __restrict__ Pq, const float* __restrict__ Pk,
    const float* __restrict__ Pv, short* __restrict__ Wt) {
  const int idx = blockIdx.x * 256 + threadIdx.x;   // n*256 + d/4
  const int n = idx >> 8, d0 = (idx & 255) * 4;
  const int which = n >> 10, h = (n >> 6) & 15, kc = n & 63;
  const float* P = (which == 0) ? Pq : (which == 1) ? Pk : Pv;
  const float* p = P + ((size_t)h * D_ + d0) * 64 + kc;
  u16x4 o;
  o[0] = f2b(p[0]); o[1] = f2b(p[64]); o[2] = f2b(p[128]); o[3] = f2b(p[192]);
  *(u16x4*)(Wt + (size_t)n * D_ + d0) = o;
}

// Wo[d][h*64+v] = P_o[h][d][v]
__global__ __launch_bounds__(256) void convert_wo_kernel(
    const float* __restrict__ Po, short* __restrict__ Wo) {
  const int idx = blockIdx.x * 256 + threadIdx.x;   // d*256 + hv/4
  const int d = idx >> 8, hv0 = (idx & 255) * 4;
  const int h = hv0 >> 6, v = hv0 & 63;
  float4 a = *(const float4*)(Po + ((size_t)h * D_ + d) * 64 + v);
  u16x4 o;
  o[0] = f2b(a.x); o[1] = f2b(a.y); o[2] = f2b(a.z); o[3] = f2b(a.w);
  *(u16x4*)(Wo + (size_t)d * 1024 + hv0) = o;
}

// ---------------------------------------------------------------------------
// Single-buffered m97-style GEMM body: C-tile 128x128, BK=64, K=1024,
// 256 threads (4 waves = 2x2, each 64x64). LDS 32 KB -> with VGPR ~108 this
// gives ~4 co-resident blocks/CU: inter-block overlap fills the stage/drain
// stalls (m114 mechanism; m97 measured 874-912 TF with this structure).
// Per K-tile: sync (readers done) -> stage(kt) -> sync (vmcnt drain) ->
//   2 x { 8 ds_read_b128 + 16 MFMA }.
// ---------------------------------------------------------------------------
__device__ __forceinline__ void gemm_body_sb(
    const char* __restrict__ Agc, const char* __restrict__ Bgc,
    short* As, short* Bs, int t, int w, int lane,
    f32x4 (&acc)[4][4])
{
  const int wr = (w >> 1) * 64, wc = (w & 1) * 64;
  const int lrow = lane & 15, lgrp = lane >> 4;

  for (int kt = 0; kt < 16; ++kt) {
    __syncthreads();                         // all waves done reading LDS
    const int d2 = kt * 128;                 // K-offset in bytes
#pragma unroll
    for (int i = 0; i < 4; ++i) {            // 128 rows x 128B each side
      const int L = i * 4096 + t * 16;
      const int row = L >> 7;
      const int cs = (L & 127) ^ ((row & 7) << 4);
      GLOAD16(Agc + (size_t)row * 2048 + d2 + cs, (char*)As + L);
      GLOAD16(Bgc + (size_t)row * 2048 + d2 + cs, (char*)Bs + L);
    }
    __syncthreads();                         // drains vmcnt -> tile visible
#pragma unroll
    for (int ks = 0; ks < 2; ++ks) {
      bf16x8 a[4], b[4];
      const int cb = ks * 64 + lgrp * 16;
#pragma unroll
      for (int f = 0; f < 4; ++f) {
        a[f] = *(const bf16x8*)((const char*)As + swzb((wr + f * 16 + lrow) * 128 + cb));
        b[f] = *(const bf16x8*)((const char*)Bs + swzb((wc + f * 16 + lrow) * 128 + cb));
      }
      __builtin_amdgcn_s_setprio(1);
#pragma unroll
      for (int mf = 0; mf < 4; ++mf)
#pragma unroll
        for (int nf = 0; nf < 4; ++nf)
          acc[mf][nf] = MFMA16(a[mf], b[nf], acc[mf][nf]);
      __builtin_amdgcn_s_setprio(0);
    }
  }
}

// ---------------------------------------------------------------------------
// QKV projection GEMM: C[8192][3072] = xb[8192][1024] @ Wt[3072][1024]^T
// 1536 blocks: xcd = bid&7 owns m-tiles [xcd*8, xcd*8+8) x all 24 n-tiles,
// m-inner (A-octet 2MB L2-resident, B streamed once; FETCH ~= ideal, r8).
// ---------------------------------------------------------------------------
__global__ __launch_bounds__(256) void qkv_gemm_kernel(
    const short* __restrict__ xb, const short* __restrict__ Wt,
    short* __restrict__ Qw, short* __restrict__ Kw, short* __restrict__ Vt) {
  __shared__ short As[8192];
  __shared__ short Bs[8192];
  const int bid = blockIdx.x;                 // 1536
  const int xcd = bid & 7, slot = bid >> 3;   // slot 0..191
  const int m0 = (xcd * 8 + (slot & 7)) * 128;
  const int n0 = (slot >> 3) * 128;
  const int t = threadIdx.x, lane = t & 63, w = t >> 6;

  f32x4 acc[4][4] = {};
  gemm_body_sb((const char*)xb + (size_t)m0 * 2048,
               (const char*)Wt + (size_t)n0 * 2048,
               As, Bs, t, w, lane, acc);

  const int wr = (w >> 1) * 64, wc = (w & 1) * 64;
  const int lrow = lane & 15, lgrp = lane >> 4;
#pragma unroll
  for (int nf = 0; nf < 4; ++nf) {
    const int n = n0 + wc + nf * 16 + lrow;
    const int which = n >> 10, h = (n >> 6) & 15, kc = n & 63;
#pragma unroll
    for (int mf = 0; mf < 4; ++mf) {
      const int row0 = m0 + wr + mf * 16 + lgrp * 4;
      const int b = row0 >> 11, mm = row0 & 2047;
      const int bh = b * 16 + h;
      if (which == 2) {
        u16x4 o;
        o[0] = f2b(acc[mf][nf][0]); o[1] = f2b(acc[mf][nf][1]);
        o[2] = f2b(acc[mf][nf][2]); o[3] = f2b(acc[mf][nf][3]);
        *(u16x4*)(Vt + ((size_t)bh * 64 + kc) * M_ + mm) = o;
      } else {
        short* outp = (which == 0 ? Qw : Kw) + ((size_t)bh * M_ + mm) * 64 + kc;
        const float scale = (which == 0) ? QSCALE : 1.0f;
#pragma unroll
        for (int r = 0; r < 4; ++r)
          outp[(size_t)r * 64] = (short)f2b(acc[mf][nf][r] * scale);
      }
    }
  }
}

// ---------------------------------------------------------------------------
// Output projection: y[8192][1024] = O2[8192][1024](bf16) @ Wo[1024][1024]^T
// 512 blocks: xcd owns 8 m-tiles x 8 n-tiles.
// ---------------------------------------------------------------------------
__global__ __launch_bounds__(256) void out_gemm_kernel(
    const short* __restrict__ O2, const short* __restrict__ Wo,
    float* __restrict__ y) {
  __shared__ short As[8192];
  __shared__ short Bs[8192];
  const int bid = blockIdx.x;                 // 512
  const int xcd = bid & 7, slot = bid >> 3;   // slot 0..63
  const int m0 = (xcd * 8 + (slot & 7)) * 128;
  const int n0 = (slot >> 3) * 128;
  const int t = threadIdx.x, lane = t & 63, w = t >> 6;

  f32x4 acc[4][4] = {};
  gemm_body_sb((const char*)O2 + (size_t)m0 * 2048,
               (const char*)Wo + (size_t)n0 * 2048,
               As, Bs, t, w, lane, acc);

  const int wr = (w >> 1) * 64, wc = (w & 1) * 64;
  const int lrow = lane & 15, lgrp = lane >> 4;
#pragma unroll
  for (int mf = 0; mf < 4; ++mf)
#pragma unroll
    for (int nf = 0; nf < 4; ++nf) {
      const int n = n0 + wc + nf * 16 + lrow;
      const int row0 = m0 + wr + mf * 16 + lgrp * 4;
#pragma unroll
      for (int r = 0; r < 4; ++r)
        y[(size_t)(row0 + r) * 1024 + n] = acc[mf][nf][r];
    }
}

// ---------------------------------------------------------------------------
// Attention helpers (unchanged)
// ---------------------------------------------------------------------------
__device__ __forceinline__ void softmax_chunk(
    f32x16& s0, f32x16& s1, f32x16& o0, f32x16& o1,
    float& mrun, float& lrun, bf16x8 (&pf)[4])
{
  float tm[16];
#pragma unroll
  for (int r = 0; r < 16; ++r) tm[r] = fmaxf(s0[r], s1[r]);
#pragma unroll
  for (int st = 8; st > 0; st >>= 1)
#pragma unroll
    for (int r = 0; r < 8; ++r)
      if (r < st) tm[r] = fmaxf(tm[r], tm[r + st]);
  uint2v pm = __builtin_amdgcn_permlane32_swap(
      __float_as_uint(tm[0]), __float_as_uint(tm[0]), false, false);
  const float mtile = fmaxf(__uint_as_float(pm[0]), __uint_as_float(pm[1]));

  if (!__all(mtile <= mrun + 8.0f)) {
    const float mnew = fmaxf(mrun, mtile);
    const float alpha = __builtin_amdgcn_exp2f(mrun - mnew);
    mrun = mnew;
    lrun *= alpha;
    o0 *= alpha;
    o1 *= alpha;
  }
#pragma unroll
  for (int r = 0; r < 16; ++r) {
    s0[r] = __builtin_amdgcn_exp2f(s0[r] - mrun);
    s1[r] = __builtin_amdgcn_exp2f(s1[r] - mrun);
  }
#pragma unroll
  for (int c = 0; c < 4; ++c) {
    const f32x16& sv = (c < 2) ? s0 : s1;
    const int rb = (c & 1) * 8;
    unsigned a0 = cvtpk(sv[rb + 0], sv[rb + 1]);
    unsigned a1 = cvtpk(sv[rb + 2], sv[rb + 3]);
    unsigned b0 = cvtpk(sv[rb + 4], sv[rb + 5]);
    unsigned b1 = cvtpk(sv[rb + 6], sv[rb + 7]);
    uint2v t0 = __builtin_amdgcn_permlane32_swap(a0, b0, false, false);
    uint2v t1 = __builtin_amdgcn_permlane32_swap(a1, b1, false, false);
    union { unsigned u[4]; bf16x8 v; } pk;
    pk.u[0] = t0[0]; pk.u[1] = t1[0]; pk.u[2] = t0[1]; pk.u[3] = t1[1];
    pf[c] = pk.v;
  }
}

// ---------------------------------------------------------------------------
// Flash attention (unchanged from r8)
// ---------------------------------------------------------------------------
__global__ __launch_bounds__(256) void attn_kernel(
    const short* __restrict__ Qw, const short* __restrict__ Kw,
    const short* __restrict__ Vt, short* __restrict__ O2) {
  __shared__ short Ks[2][64 * 64];
  __shared__ short Vs[2][64 * 64];

  const int bid = blockIdx.x;                 // 1024 blocks
  const int chunk = 15 - (bid >> 6);          // heavy-first
  const int bh = bid & 63;                    // bh%8 == dispatch XCD
  const int q0 = chunk * 128;

  const int t = threadIdx.x, lane = t & 63, w = t >> 6;
  const int l31 = lane & 31, hi = lane >> 5;
  const int qw0 = q0 + w * 32;
  const int qabs = qw0 + l31;

  bf16x8 qfrag[4];
#pragma unroll
  for (int kc = 0; kc < 4; ++kc)
    qfrag[kc] = *(const bf16x8*)(Qw + ((size_t)bh * M_ + qabs) * 64 + kc * 16 + hi * 8);

  f32x16 o0 = {}, o1 = {};
  float mrun = -3.0e38f, lrun = 0.f;

  const char* Kg = (const char*)Kw + (size_t)bh * M_ * 128;
  const char* Vg = (const char*)Vt + (size_t)bh * 64 * M_ * 2;

  auto stage = [&](int bi, int j0_) {
#pragma unroll
    for (int i = 0; i < 2; ++i) {
      const int L  = i * 4096 + t * 16;
      const int Ls = SWZ256(L);
      const int row = Ls >> 7, col = Ls & 127;
      GLOAD16(Kg + (size_t)(j0_ + row) * 128 + col, (char*)Ks[bi] + i * 4096 + w * 1024);
      GLOAD16(Vg + (size_t)row * (M_ * 2) + (size_t)j0_ * 2 + col, (char*)Vs[bi] + i * 4096 + w * 1024);
    }
  };

  const int nt = (q0 + 128) >> 6;
  stage(0, 0);

  bf16x8 ones;
#pragma unroll
  for (int e = 0; e < 8; ++e) ones[e] = (short)0x3F80;

  for (int tt = 0; tt < nt; ++tt) {
    const int j0 = tt << 6;
    const int cur = tt & 1;
    __builtin_amdgcn_s_barrier();
    if (tt + 1 < nt) {
      stage(cur ^ 1, j0 + 64);
      asm volatile("s_waitcnt vmcnt(4)" ::: "memory");
    } else {
      asm volatile("s_waitcnt vmcnt(0)" ::: "memory");
    }
    __builtin_amdgcn_s_barrier();
    if (j0 >= qw0 + 32) continue;

    const char* Kc = (const char*)Ks[cur];
    const char* Vc = (const char*)Vs[cur];

    f32x16 s0 = {}, s1 = {};
    __builtin_amdgcn_s_setprio(1);
#pragma unroll
    for (int kc = 0; kc < 4; ++kc) {
      bf16x8 kf0 = *(const bf16x8*)(Kc + SWZ256(l31 * 128 + kc * 32 + hi * 16));
      s0 = MFMA32(kf0, qfrag[kc], s0);
      bf16x8 kf1 = *(const bf16x8*)(Kc + SWZ256((32 + l31) * 128 + kc * 32 + hi * 16));
      s1 = MFMA32(kf1, qfrag[kc], s1);
    }
    __builtin_amdgcn_s_setprio(0);

    if (j0 + 64 > qw0) {
#pragma unroll
      for (int r = 0; r < 16; ++r) {
        const int k0 = j0 + (r & 3) + 8 * (r >> 2) + 4 * hi;
        if (k0 > qabs)      s0[r] = -3.0e38f;
        if (k0 + 32 > qabs) s1[r] = -3.0e38f;
      }
    }

    bf16x8 pf[4];
    softmax_chunk(s0, s1, o0, o1, mrun, lrun, pf);

    f32x16 lacc = {};
    __builtin_amdgcn_s_setprio(1);
#pragma unroll
    for (int c = 0; c < 4; ++c) {
      bf16x8 vf0 = *(const bf16x8*)(Vc + SWZ256(l31 * 128 + c * 32 + hi * 16));
      o0 = MFMA32(vf0, pf[c], o0);
      bf16x8 vf1 = *(const bf16x8*)(Vc + SWZ256((32 + l31) * 128 + c * 32 + hi * 16));
      o1 = MFMA32(vf1, pf[c], o1);
      lacc = MFMA32(ones, pf[c], lacc);
    }
    __builtin_amdgcn_s_setprio(0);
    lrun += lacc[0];
  }

  const int b = bh >> 4, h = bh & 15;
  const float inv = 1.0f / lrun;
  short* orow = O2 + ((size_t)b * M_ + qabs) * 1024 + h * 64;
#pragma unroll
  for (int vb = 0; vb < 2; ++vb) {
    const f32x16& o = vb ? o1 : o0;
#pragma unroll
    for (int g = 0; g < 4; ++g) {
      const int vbase = vb * 32 + 8 * g + 4 * hi;
      u16x4 pkt;
      pkt[0] = f2b(o[g * 4 + 0] * inv);
      pkt[1] = f2b(o[g * 4 + 1] * inv);
      pkt[2] = f2b(o[g * 4 + 2] * inv);
      pkt[3] = f2b(o[g * 4 + 3] * inv);
      *(u16x4*)(orow + vbase) = pkt;
    }
  }
}

// ---------------------------------------------------------------------------
extern "C" void kernel_launch(void* const* d_in, const int* in_sizes, int n_in,
                              void* d_out, int out_size, void* d_ws, size_t ws_size,
                              hipStream_t stream) {
  const float* x  = (const float*)d_in[0];
  const float* Pq = (const float*)d_in[1];
  const float* Pk = (const float*)d_in[2];
  const float* Pv = (const float*)d_in[3];
  const float* Po = (const float*)d_in[4];
  float* y = (float*)d_out;

  short* ws = (short*)d_ws;
  const size_t NX = (size_t)B_ * M_ * D_;        // 8,388,608
  short* xb  = ws;                 ws += NX;
  short* Wt  = ws;                 ws += (size_t)3072 * 1024;
  short* Wo  = ws;                 ws += (size_t)1024 * 1024;
  short* Qw  = ws;                 ws += NX;
  short* Kw  = ws;                 ws += NX;
  short* Vt  = ws;                 ws += NX;
  short* O2  = ws;                 ws += NX;

  convert_x_kernel <<<4096, 256, 0, stream>>>(x, xb);
  convert_w_kernel <<<3072, 256, 0, stream>>>(Pq, Pk, Pv, Wt);
  convert_wo_kernel<<<1024, 256, 0, stream>>>(Po, Wo);
  qkv_gemm_kernel  <<<1536, 256, 0, stream>>>(xb, Wt, Qw, Kw, Vt);
  attn_kernel      <<<1024, 256, 0, stream>>>(Qw, Kw, Vt, O2);
  out_gemm_kernel  <<<512,  256, 0, stream>>>(O2, Wo, y);
}